// Round 1
// baseline (48.281 us; speedup 1.0000x reference)
//
#include <hip/hip_runtime.h>
#include <hip/hip_bf16.h>

// RotateChordVarLen: x [T, 256] f32, 16 tracks of 16 floats.
// out[t, track i] = x[start + (pos + shift_i) % len, track i],
// shift_0 = 0, shift_i = 2^(i-1).
//
// Mapping: one wave per token. lane l -> track l/4, float4 quad l%4.
// Writes perfectly coalesced (1 KiB/wave); reads are 16 x 64B contiguous
// chunks per wave (fully-utilized 64B transactions, streaming locality).

__global__ __launch_bounds__(256) void
rotate_chord_kernel(const float* __restrict__ x,
                    const int* __restrict__ lengths,
                    float* __restrict__ out,
                    int T, int B) {
    int gid  = blockIdx.x * blockDim.x + threadIdx.x;
    int t    = gid >> 6;           // token index (wave-uniform)
    if (t >= T) return;
    int lane  = gid & 63;
    int track = lane >> 2;         // 0..15
    int quad  = lane & 3;          // 0..3 (float4 within the 16-float track)

    // Segment search over B (=8) segments — wave-uniform, tiny.
    int start = 0, len = 1;
    int acc = 0;
    for (int b = 0; b < B; ++b) {
        int L = lengths[b];
        if (t >= acc) { start = acc; len = L; }
        acc += L;
    }
    int pos = t - start;

    int shift = (track == 0) ? 0 : (1 << (track - 1));
    int sp = pos + shift;
    sp -= (sp / len) * len;        // (pos + shift) % len ; shift may exceed len
    int src = start + sp;

    const float4* __restrict__ xr =
        reinterpret_cast<const float4*>(x + (size_t)src * 256 + track * 16 + quad * 4);
    float4 v = *xr;
    *reinterpret_cast<float4*>(out + (size_t)t * 256 + (size_t)lane * 4) = v;
}

extern "C" void kernel_launch(void* const* d_in, const int* in_sizes, int n_in,
                              void* d_out, int out_size, void* d_ws, size_t ws_size,
                              hipStream_t stream) {
    const float* x       = (const float*)d_in[0];
    const int*   lengths = (const int*)d_in[1];
    float*       out     = (float*)d_out;

    const int D = 256;
    int T = in_sizes[0] / D;
    int B = in_sizes[1];

    // T*64 lanes total, 256 threads/block -> T/4 blocks (T is a multiple of 4 here,
    // but round up to be safe).
    long long total_threads = (long long)T * 64;
    int blocks = (int)((total_threads + 255) / 256);

    rotate_chord_kernel<<<blocks, 256, 0, stream>>>(x, lengths, out, T, B);
}